// Round 5
// baseline (3729.536 us; speedup 1.0000x reference)
//
#include <hip/hip_runtime.h>
#include <math.h>

#define B_ 8
#define N_ 2048
#define H_ 128
#define BN_ (B_ * N_)

// ws layout: A [BN][H] f32 | C [BN][H] f32 | K [B][N][N] u32 (sortable keys)
// need = 2*8MB + 128MB = 150,994,944 bytes

__device__ __forceinline__ float elu1(float x) {
    return x > 0.f ? x : (__expf(x) - 1.f);
}

// Order-preserving bijection f32 -> u32 (and exact inverse).
__device__ __forceinline__ unsigned enc_key(float v) {
    unsigned u = __float_as_uint(v);
    return (u & 0x80000000u) ? ~u : (u | 0x80000000u);
}
__device__ __forceinline__ float dec_key(unsigned k) {
    return __uint_as_float((k & 0x80000000u) ? (k & 0x7FFFFFFFu) : ~k);
}

// ---------------- K1: A = emb@W1[:H] ; C = emb@W1[H:] + b1 ----------------
// NUMERICS FROZEN (passed absmax=0 x4) — do not reorder the fma chain.
__global__ __launch_bounds__(H_) void k_ac(const float* __restrict__ emb,
                                           const float* __restrict__ W1,
                                           const float* __restrict__ b1,
                                           float* __restrict__ A,
                                           float* __restrict__ C) {
    __shared__ float e[H_];
    const int i = blockIdx.x;
    const int k = threadIdx.x;
    e[k] = emb[(size_t)i * H_ + k];
    __syncthreads();
    float a = 0.f, c = 0.f;
#pragma unroll 8
    for (int h = 0; h < H_; ++h) {
        const float ev = e[h];
        a = fmaf(ev, W1[h * H_ + k], a);
        c = fmaf(ev, W1[(H_ + h) * H_ + k], c);
    }
    A[(size_t)i * H_ + k] = a;
    C[(size_t)i * H_ + k] = c + b1[k];
}

// ---------------- K2: K[g][i][j] = enc_key(w2 . elu(A_i + C_j) + b2) -------
// z NUMERICS FROZEN: per-value op sequence identical to r1-r4 (8-fma chain in
// h order, then shfl_xor 4/8/16/32, then +b2). 8-wide j-unroll only adds ILP
// across independent values — bit-exact.
__global__ __launch_bounds__(256) void k_z(const float* __restrict__ A,
                                           const float* __restrict__ Cc,
                                           const float* __restrict__ w2,
                                           const float* __restrict__ b2p,
                                           unsigned* __restrict__ K) {
    const int lane = threadIdx.x & 63;
    const int wave = threadIdx.x >> 6;          // 0..3
    const int g = blockIdx.x >> 8;              // 256 blocks per graph
    const int sub = blockIdx.x & 255;
    const int rowtile = sub & 127;
    const int jh = sub >> 7;
    const int ibase = rowtile * 16 + wave * 4;
    const int i = ibase + (lane & 3);           // this group's row
    const int he = (lane >> 2) * 8;             // h-slice start (0..120)
    const float b2v = *b2p;

    const float* Arow = A + ((size_t)g * N_ + i) * H_ + he;
    const float4 a0 = *(const float4*)(Arow);
    const float4 a1 = *(const float4*)(Arow + 4);
    const float4 w0 = *(const float4*)(w2 + he);
    const float4 w1v = *(const float4*)(w2 + he + 4);
    const float* Cg = Cc + (size_t)g * N_ * H_ + he;
    unsigned* Krow = K + ((size_t)g * N_ + i) * N_;
    const bool writer = ((lane >> 2) == 0);

    const int j0 = jh * 1024;
    for (int j = j0; j < j0 + 1024; j += 8) {
        float4 c0[8], c1[8];
#pragma unroll
        for (int q = 0; q < 8; ++q) {
            const float* Cj = Cg + (size_t)(j + q) * H_;
            c0[q] = *(const float4*)(Cj);
            c1[q] = *(const float4*)(Cj + 4);
        }
        float pv[8];
#pragma unroll
        for (int q = 0; q < 8; ++q) {
            float p = 0.f;
            p = fmaf(w0.x, elu1(a0.x + c0[q].x), p);
            p = fmaf(w0.y, elu1(a0.y + c0[q].y), p);
            p = fmaf(w0.z, elu1(a0.z + c0[q].z), p);
            p = fmaf(w0.w, elu1(a0.w + c0[q].w), p);
            p = fmaf(w1v.x, elu1(a1.x + c1[q].x), p);
            p = fmaf(w1v.y, elu1(a1.y + c1[q].y), p);
            p = fmaf(w1v.z, elu1(a1.z + c1[q].z), p);
            p = fmaf(w1v.w, elu1(a1.w + c1[q].w), p);
            pv[q] = p;
        }
        // 8 independent shuffle-reduce chains (same per-value order as r1-r4)
#pragma unroll
        for (int q = 0; q < 8; ++q) pv[q] += __shfl_xor(pv[q], 4);
#pragma unroll
        for (int q = 0; q < 8; ++q) pv[q] += __shfl_xor(pv[q], 8);
#pragma unroll
        for (int q = 0; q < 8; ++q) pv[q] += __shfl_xor(pv[q], 16);
#pragma unroll
        for (int q = 0; q < 8; ++q) pv[q] += __shfl_xor(pv[q], 32);
        if (writer) {
            uint4 ka, kb;
            ka.x = enc_key(pv[0] + b2v);
            ka.y = enc_key(pv[1] + b2v);
            ka.z = enc_key(pv[2] + b2v);
            ka.w = enc_key(pv[3] + b2v);
            kb.x = enc_key(pv[4] + b2v);
            kb.y = enc_key(pv[5] + b2v);
            kb.z = enc_key(pv[6] + b2v);
            kb.w = enc_key(pv[7] + b2v);
            *(uint4*)(Krow + j) = ka;
            *(uint4*)(Krow + j + 4) = kb;
        }
    }
}

// ---------------- K3: greedy chain + runner-up speculative prefetch --------
// Register vis bitmask, no LDS/barriers (r4). New: after the winner butterfly,
// a second butterfly over (lanebest minus winner) yields the exact global
// runner-up; its row is prefetched into z2. If the next step's winner equals
// the prediction, the row is already in registers -> load latency hidden.
// Exactness is independent of hit rate (reduce always runs on true row).
__global__ __launch_bounds__(64, 1) void k_path4(const float* __restrict__ emb,
                                                 const unsigned* __restrict__ K,
                                                 float* __restrict__ out) {
    const int g = blockIdx.x;
    const int lane = threadIdx.x;  // 0..63

    // per-slot low words (~j), invariant across steps — lives in registers
    unsigned lo[32];
#pragma unroll
    for (int k = 0; k < 8; ++k)
#pragma unroll
        for (int e = 0; e < 4; ++e)
            lo[k * 4 + e] = ~(unsigned)(k * 256 + (lane << 2) + e);

    // root = argmax_j emb[g][j][0], first-max tie-break
    float bv0 = -INFINITY;
    int bi0 = 0x7fffffff;
    for (int j = lane; j < N_; j += 64) {
        const float v = emb[((size_t)g * N_ + j) * H_];
        if (v > bv0) { bv0 = v; bi0 = j; }  // ascending j per lane => first max
    }
#pragma unroll
    for (int off = 1; off < 64; off <<= 1) {
        const float ov = __shfl_xor(bv0, off);
        const int oi = __shfl_xor(bi0, off);
        if (ov > bv0 || (ov == bv0 && oi < bi0)) { bv0 = ov; bi0 = oi; }
    }
    int cur = bi0;
    unsigned vbits = 0;
    if (((cur >> 2) & 63) == lane)
        vbits |= 1u << (((cur >> 8) << 2) | (cur & 3));

    float* pathOut = out + (size_t)g * N_;
    float* scoreOut = out + (size_t)BN_ + (size_t)g * N_;
    if (lane == 0) {
        pathOut[0] = (float)cur;
        scoreOut[0] = 1.0f;
    }

    const unsigned* Kg = K + (size_t)g * N_ * N_;
    // slot layout: uint4 index k*64+lane == elements k*256 + 4*lane .. +3
    uint4 z[8], z2[8];
    {
        const uint4* Kr = (const uint4*)(Kg + ((size_t)cur << 11));
#pragma unroll
        for (int k = 0; k < 8; ++k) z[k] = Kr[k * 64 + lane];
    }
    int pred = -1;  // no prediction for step 1

    int t = 1;
    for (; t < N_; ++t) {
        // pack: visited -> hi=0 (any valid key wins); lo = ~j constant
        unsigned long long kk[32];
#pragma unroll
        for (int k = 0; k < 8; ++k) {
            const unsigned zx = z[k].x, zy = z[k].y, zz = z[k].z, zw = z[k].w;
            const int b = k * 4;
            kk[b + 0] = ((unsigned long long)(((vbits >> (b + 0)) & 1u) ? 0u : zx) << 32) | lo[b + 0];
            kk[b + 1] = ((unsigned long long)(((vbits >> (b + 1)) & 1u) ? 0u : zy) << 32) | lo[b + 1];
            kk[b + 2] = ((unsigned long long)(((vbits >> (b + 2)) & 1u) ? 0u : zz) << 32) | lo[b + 2];
            kk[b + 3] = ((unsigned long long)(((vbits >> (b + 3)) & 1u) ? 0u : zw) << 32) | lo[b + 3];
        }
        // in-lane 5-level tree (static indices -> registers)
#pragma unroll
        for (int s = 16; s >= 1; s >>= 1)
#pragma unroll
            for (int i = 0; i < s; ++i)
                if (kk[i + s] > kk[i]) kk[i] = kk[i + s];
        const unsigned long long lanebest = kk[0];
        unsigned long long key = lanebest;
        // cross-lane butterfly, 6 rounds of u64 max
#pragma unroll
        for (int off = 1; off < 64; off <<= 1) {
            const unsigned long long ok = __shfl_xor(key, off);
            if (ok > key) key = ok;
        }
        const int bi = (int)(~(unsigned)key);  // j = ~low32

        // next row's data: prediction hit -> registers; miss -> issue loads NOW
        if (bi == pred) {
#pragma unroll
            for (int k = 0; k < 8; ++k) z[k] = z2[k];
        } else {
            const uint4* Kr = (const uint4*)(Kg + ((size_t)bi << 11));
#pragma unroll
            for (int k = 0; k < 8; ++k) z[k] = Kr[k * 64 + lane];
        }

        // exact global runner-up (winner's lane key removed; keys are unique)
        unsigned long long pk = (lanebest == key) ? 0ull : lanebest;
#pragma unroll
        for (int off = 1; off < 64; off <<= 1) {
            const unsigned long long ok = __shfl_xor(pk, off);
            if (ok > pk) pk = ok;
        }
        int np = (pk == 0ull) ? -1 : (int)(~(unsigned)pk);
        {
            const int safe = (np >= 0) ? np : bi;  // always a valid row id
            const uint4* Kr2 = (const uint4*)(Kg + ((size_t)safe << 11));
#pragma unroll
            for (int k = 0; k < 8; ++k) z2[k] = Kr2[k * 64 + lane];
        }
        pred = np;

        const float bv = dec_key((unsigned)(key >> 32));
        const float s = 1.f / (1.f + expf(-bv));
        if (!((double)s > 0.3)) break;  // frozen break form (passed r1-r4)
        cur = bi;
        if (((cur >> 2) & 63) == lane)
            vbits |= 1u << (((cur >> 8) << 2) | (cur & 3));
        if (lane == 0) {
            pathOut[t] = (float)cur;
            scoreOut[t] = s;
        }
    }
    for (int tt = t + lane; tt < N_; tt += 64) {
        pathOut[tt] = -1.f;
        scoreOut[tt] = 0.f;
    }
}

// ---------------- Fallback: on-the-fly scoring (ws too small for K) --------
__device__ __forceinline__ void blockArgmax(float& bv, int& bi, float* rv, int* ri,
                                            int lane, int wid, int nw) {
#pragma unroll
    for (int off = 1; off < 64; off <<= 1) {
        const float ov = __shfl_xor(bv, off);
        const int oi = __shfl_xor(bi, off);
        if (ov > bv || (ov == bv && oi < bi)) { bv = ov; bi = oi; }
    }
    if (lane == 0) { rv[wid] = bv; ri[wid] = bi; }
    __syncthreads();
    if (wid == 0) {
        float v = (lane < nw) ? rv[lane] : -INFINITY;
        int ix = (lane < nw) ? ri[lane] : 0x7fffffff;
#pragma unroll
        for (int off = 1; off < 16; off <<= 1) {
            const float ov = __shfl_xor(v, off);
            const int oi = __shfl_xor(ix, off);
            if (ov > v || (ov == v && oi < ix)) { v = ov; ix = oi; }
        }
        if (lane == 0) { rv[0] = v; ri[0] = ix; }
    }
    __syncthreads();
    bv = rv[0];
    bi = ri[0];
}

__global__ __launch_bounds__(1024) void k_path_fly(const float* __restrict__ emb,
                                                   const float* __restrict__ A,
                                                   const float* __restrict__ Cc,
                                                   const float* __restrict__ w2g,
                                                   const float* __restrict__ b2p,
                                                   float* __restrict__ out) {
    const int g = blockIdx.x;
    const int tid = threadIdx.x;
    const int lane = tid & 63, wid = tid >> 6;
    __shared__ float acur[H_], w2s[H_];
    __shared__ unsigned char vis[N_];
    __shared__ float rv[16];
    __shared__ int ri[16];
    const float b2v = *b2p;
    if (tid < H_) w2s[tid] = w2g[tid];
    for (int j = tid; j < N_; j += 1024) vis[j] = 0;

    float bv = -INFINITY;
    int bi = 0x7fffffff;
    for (int j = tid; j < N_; j += 1024) {
        const float v = emb[((size_t)g * N_ + j) * H_];
        if (v > bv) { bv = v; bi = j; }
    }
    __syncthreads();
    blockArgmax(bv, bi, rv, ri, lane, wid, 16);
    int cur = bi;
    float* pathOut = out + (size_t)g * N_;
    float* scoreOut = out + (size_t)BN_ + (size_t)g * N_;
    if (tid == 0) {
        vis[cur] = 1;
        pathOut[0] = (float)cur;
        scoreOut[0] = 1.0f;
    }
    __syncthreads();

    int t = 1;
    for (; t < N_; ++t) {
        if (tid < H_) acur[tid] = A[((size_t)g * N_ + cur) * H_ + tid];
        __syncthreads();
        float mbv = -INFINITY;
        int mbi = 0x7fffffff;
#pragma unroll
        for (int q = 0; q < 2; ++q) {
            const int j = tid + q * 1024;
            const float* Cj = Cc + ((size_t)g * N_ + j) * H_;
            float p = 0.f;
            for (int h = 0; h < H_; h += 4) {
                const float4 c = *(const float4*)(Cj + h);
                p = fmaf(w2s[h + 0], elu1(acur[h + 0] + c.x), p);
                p = fmaf(w2s[h + 1], elu1(acur[h + 1] + c.y), p);
                p = fmaf(w2s[h + 2], elu1(acur[h + 2] + c.z), p);
                p = fmaf(w2s[h + 3], elu1(acur[h + 3] + c.w), p);
            }
            const float z = p + b2v;
            if (!vis[j] && (z > mbv || (z == mbv && j < mbi))) { mbv = z; mbi = j; }
        }
        __syncthreads();
        blockArgmax(mbv, mbi, rv, ri, lane, wid, 16);
        const float s = 1.f / (1.f + expf(-mbv));
        if (!((double)s > 0.3)) break;
        cur = mbi;
        if (tid == 0) {
            vis[cur] = 1;
            pathOut[t] = (float)cur;
            scoreOut[t] = s;
        }
        __syncthreads();
    }
    for (int tt = t + tid; tt < N_; tt += 1024) {
        pathOut[tt] = -1.f;
        scoreOut[tt] = 0.f;
    }
}

extern "C" void kernel_launch(void* const* d_in, const int* in_sizes, int n_in,
                              void* d_out, int out_size, void* d_ws, size_t ws_size,
                              hipStream_t stream) {
    (void)in_sizes; (void)n_in; (void)out_size;
    const float* emb = (const float*)d_in[0];
    // d_in[1] = batch (int64) — contiguous equal-sized graphs, unused
    const float* W1 = (const float*)d_in[2];
    const float* b1 = (const float*)d_in[3];
    const float* w2 = (const float*)d_in[4];
    const float* b2 = (const float*)d_in[5];
    float* out = (float*)d_out;

    float* A = (float*)d_ws;
    float* C = A + (size_t)BN_ * H_;
    unsigned* K = (unsigned*)(C + (size_t)BN_ * H_);
    const size_t need = ((size_t)BN_ * H_ * 2 + (size_t)B_ * N_ * N_) * sizeof(float);

    hipLaunchKernelGGL(k_ac, dim3(BN_), dim3(H_), 0, stream, emb, W1, b1, A, C);
    if (ws_size >= need) {
        hipLaunchKernelGGL(k_z, dim3(2048), dim3(256), 0, stream, A, C, w2, b2, K);
        hipLaunchKernelGGL(k_path4, dim3(B_), dim3(64), 0, stream, emb, K, out);
    } else {
        hipLaunchKernelGGL(k_path_fly, dim3(B_), dim3(1024), 0, stream,
                           emb, A, C, w2, b2, out);
    }
}

// Round 6
// 3217.946 us; speedup vs baseline: 1.1590x; 1.1590x over previous
//
#include <hip/hip_runtime.h>
#include <math.h>

#define B_ 8
#define N_ 2048
#define H_ 128
#define BN_ (B_ * N_)

// ws layout: A [BN][H] f32 | C [BN][H] f32 | K [B][N][N] u32 (sortable keys)
// need = 2*8MB + 128MB = 150,994,944 bytes

__device__ __forceinline__ float elu1(float x) {
    return x > 0.f ? x : (__expf(x) - 1.f);
}

// Order-preserving bijection f32 -> u32 (and exact inverse).
// Finite floats never map to 0 (min key = enc(-FLT_MAX) = 0x00800000).
__device__ __forceinline__ unsigned enc_key(float v) {
    unsigned u = __float_as_uint(v);
    return (u & 0x80000000u) ? ~u : (u | 0x80000000u);
}
__device__ __forceinline__ float dec_key(unsigned k) {
    return __uint_as_float((k & 0x80000000u) ? (k & 0x7FFFFFFFu) : ~k);
}

// ---------------- K1: A = emb@W1[:H] ; C = emb@W1[H:] + b1 ----------------
// NUMERICS FROZEN (passed absmax=0 x5) — do not reorder the fma chain.
__global__ __launch_bounds__(H_) void k_ac(const float* __restrict__ emb,
                                           const float* __restrict__ W1,
                                           const float* __restrict__ b1,
                                           float* __restrict__ A,
                                           float* __restrict__ C) {
    __shared__ float e[H_];
    const int i = blockIdx.x;
    const int k = threadIdx.x;
    e[k] = emb[(size_t)i * H_ + k];
    __syncthreads();
    float a = 0.f, c = 0.f;
#pragma unroll 8
    for (int h = 0; h < H_; ++h) {
        const float ev = e[h];
        a = fmaf(ev, W1[h * H_ + k], a);
        c = fmaf(ev, W1[(H_ + h) * H_ + k], c);
    }
    A[(size_t)i * H_ + k] = a;
    C[(size_t)i * H_ + k] = c + b1[k];
}

// ---------------- K2: K[g][i][j] = enc_key(w2 . elu(A_i + C_j) + b2) -------
// z NUMERICS FROZEN: per-value op sequence identical to r1-r5 (8-fma chain in
// h order, then shfl_xor 4/8/16/32, then +b2).
__global__ __launch_bounds__(256) void k_z(const float* __restrict__ A,
                                           const float* __restrict__ Cc,
                                           const float* __restrict__ w2,
                                           const float* __restrict__ b2p,
                                           unsigned* __restrict__ K) {
    const int lane = threadIdx.x & 63;
    const int wave = threadIdx.x >> 6;          // 0..3
    const int g = blockIdx.x >> 8;              // 256 blocks per graph
    const int sub = blockIdx.x & 255;
    const int rowtile = sub & 127;
    const int jh = sub >> 7;
    const int ibase = rowtile * 16 + wave * 4;
    const int i = ibase + (lane & 3);           // this group's row
    const int he = (lane >> 2) * 8;             // h-slice start (0..120)
    const float b2v = *b2p;

    const float* Arow = A + ((size_t)g * N_ + i) * H_ + he;
    const float4 a0 = *(const float4*)(Arow);
    const float4 a1 = *(const float4*)(Arow + 4);
    const float4 w0 = *(const float4*)(w2 + he);
    const float4 w1v = *(const float4*)(w2 + he + 4);
    const float* Cg = Cc + (size_t)g * N_ * H_ + he;
    unsigned* Krow = K + ((size_t)g * N_ + i) * N_;
    const bool writer = ((lane >> 2) == 0);

    const int j0 = jh * 1024;
    for (int j = j0; j < j0 + 1024; j += 8) {
        float4 c0[8], c1[8];
#pragma unroll
        for (int q = 0; q < 8; ++q) {
            const float* Cj = Cg + (size_t)(j + q) * H_;
            c0[q] = *(const float4*)(Cj);
            c1[q] = *(const float4*)(Cj + 4);
        }
        float pv[8];
#pragma unroll
        for (int q = 0; q < 8; ++q) {
            float p = 0.f;
            p = fmaf(w0.x, elu1(a0.x + c0[q].x), p);
            p = fmaf(w0.y, elu1(a0.y + c0[q].y), p);
            p = fmaf(w0.z, elu1(a0.z + c0[q].z), p);
            p = fmaf(w0.w, elu1(a0.w + c0[q].w), p);
            p = fmaf(w1v.x, elu1(a1.x + c1[q].x), p);
            p = fmaf(w1v.y, elu1(a1.y + c1[q].y), p);
            p = fmaf(w1v.z, elu1(a1.z + c1[q].z), p);
            p = fmaf(w1v.w, elu1(a1.w + c1[q].w), p);
            pv[q] = p;
        }
        // 8 independent shuffle-reduce chains (same per-value order as r1-r5)
#pragma unroll
        for (int q = 0; q < 8; ++q) pv[q] += __shfl_xor(pv[q], 4);
#pragma unroll
        for (int q = 0; q < 8; ++q) pv[q] += __shfl_xor(pv[q], 8);
#pragma unroll
        for (int q = 0; q < 8; ++q) pv[q] += __shfl_xor(pv[q], 16);
#pragma unroll
        for (int q = 0; q < 8; ++q) pv[q] += __shfl_xor(pv[q], 32);
        if (writer) {
            uint4 ka, kb;
            ka.x = enc_key(pv[0] + b2v);
            ka.y = enc_key(pv[1] + b2v);
            ka.z = enc_key(pv[2] + b2v);
            ka.w = enc_key(pv[3] + b2v);
            kb.x = enc_key(pv[4] + b2v);
            kb.y = enc_key(pv[5] + b2v);
            kb.z = enc_key(pv[6] + b2v);
            kb.w = enc_key(pv[7] + b2v);
            *(uint4*)(Krow + j) = ka;
            *(uint4*)(Krow + j + 4) = kb;
        }
    }
}

// ---------------- K3: greedy chain — all-32-bit reduce ---------------------
// Slot s (0..31) of lane L holds j = (s>>2)*256 + 4L + (s&3); j is monotonic
// in s. In-lane: descending-s scan with >= keeps (max key, min j). Cross-lane:
// 32-bit key butterfly, then ballot tie-break (single-lane common case).
__global__ __launch_bounds__(64, 1) void k_path5(const float* __restrict__ emb,
                                                 const unsigned* __restrict__ K,
                                                 float* __restrict__ out) {
    const int g = blockIdx.x;
    const int lane = threadIdx.x;  // 0..63

    // root = argmax_j emb[g][j][0], first-max tie-break
    float bv0 = -INFINITY;
    int bi0 = 0x7fffffff;
    for (int j = lane; j < N_; j += 64) {
        const float v = emb[((size_t)g * N_ + j) * H_];
        if (v > bv0) { bv0 = v; bi0 = j; }  // ascending j per lane => first max
    }
#pragma unroll
    for (int off = 1; off < 64; off <<= 1) {
        const float ov = __shfl_xor(bv0, off);
        const int oi = __shfl_xor(bi0, off);
        if (ov > bv0 || (ov == bv0 && oi < bi0)) { bv0 = ov; bi0 = oi; }
    }
    int cur = bi0;
    unsigned vbits = 0;
    if (((cur >> 2) & 63) == lane)
        vbits |= 1u << (((cur >> 8) << 2) | (cur & 3));

    float* pathOut = out + (size_t)g * N_;
    float* scoreOut = out + (size_t)BN_ + (size_t)g * N_;
    if (lane == 0) {
        pathOut[0] = (float)cur;
        scoreOut[0] = 1.0f;
    }

    const unsigned* Kg = K + (size_t)g * N_ * N_;
    uint4 z[8];
    {
        const uint4* Kr = (const uint4*)(Kg + ((size_t)cur << 11));
#pragma unroll
        for (int k = 0; k < 8; ++k) z[k] = Kr[k * 64 + lane];
    }

    int t = 1;
    for (; t < N_; ++t) {
        // in-lane: descending slot scan, >= keeps min-j among equal keys.
        // visited -> key 0 (finite keys are never 0).
        unsigned best = 0u;
        int bj = 0;
#define SLOT(KRAW, S)                                                   \
        {                                                               \
            const unsigned kv_ = ((vbits >> (S)) & 1u) ? 0u : (KRAW);   \
            if (kv_ >= best) { best = kv_; bj = (S); }                  \
        }
        SLOT(z[7].w, 31) SLOT(z[7].z, 30) SLOT(z[7].y, 29) SLOT(z[7].x, 28)
        SLOT(z[6].w, 27) SLOT(z[6].z, 26) SLOT(z[6].y, 25) SLOT(z[6].x, 24)
        SLOT(z[5].w, 23) SLOT(z[5].z, 22) SLOT(z[5].y, 21) SLOT(z[5].x, 20)
        SLOT(z[4].w, 19) SLOT(z[4].z, 18) SLOT(z[4].y, 17) SLOT(z[4].x, 16)
        SLOT(z[3].w, 15) SLOT(z[3].z, 14) SLOT(z[3].y, 13) SLOT(z[3].x, 12)
        SLOT(z[2].w, 11) SLOT(z[2].z, 10) SLOT(z[2].y,  9) SLOT(z[2].x,  8)
        SLOT(z[1].w,  7) SLOT(z[1].z,  6) SLOT(z[1].y,  5) SLOT(z[1].x,  4)
        SLOT(z[0].w,  3) SLOT(z[0].z,  2) SLOT(z[0].y,  1) SLOT(z[0].x,  0)
#undef SLOT

        // cross-lane: 32-bit key max
        unsigned w = best;
#pragma unroll
        for (int off = 1; off < 64; off <<= 1) {
            const unsigned ow = __shfl_xor(w, off);
            if (ow > w) w = ow;
        }
        // tie-break: which lane, which j
        const unsigned long long mk = __ballot(best == w);
        int bi;
        if (__popcll(mk) == 1) {
            const int src = (int)(__ffsll((long long)mk) - 1);
            const int bjw = __shfl(bj, src);
            bi = ((bjw >> 2) << 8) | (src << 2) | (bjw & 3);
        } else {
            // rare: value tie across lanes -> exact min-j via max(~j)
            unsigned cand = (best == w)
                ? ~(unsigned)(((bj >> 2) << 8) | (lane << 2) | (bj & 3))
                : 0u;
#pragma unroll
            for (int off = 1; off < 64; off <<= 1) {
                const unsigned oc = __shfl_xor(cand, off);
                if (oc > cand) cand = oc;
            }
            bi = (int)(~cand);
        }

        // issue next row's loads NOW; sigmoid/break/output overlap the latency
        {
            const uint4* Kr = (const uint4*)(Kg + ((size_t)bi << 11));
#pragma unroll
            for (int k = 0; k < 8; ++k) z[k] = Kr[k * 64 + lane];
        }

        const float bv = dec_key(w);
        const float s = 1.f / (1.f + expf(-bv));
        if (!((double)s > 0.3)) break;  // frozen break form (passed r1-r5)
        cur = bi;
        if (((cur >> 2) & 63) == lane)
            vbits |= 1u << (((cur >> 8) << 2) | (cur & 3));
        if (lane == 0) {
            pathOut[t] = (float)cur;
            scoreOut[t] = s;
        }
    }
    for (int tt = t + lane; tt < N_; tt += 64) {
        pathOut[tt] = -1.f;
        scoreOut[tt] = 0.f;
    }
}

// ---------------- Fallback: on-the-fly scoring (ws too small for K) --------
__device__ __forceinline__ void blockArgmax(float& bv, int& bi, float* rv, int* ri,
                                            int lane, int wid, int nw) {
#pragma unroll
    for (int off = 1; off < 64; off <<= 1) {
        const float ov = __shfl_xor(bv, off);
        const int oi = __shfl_xor(bi, off);
        if (ov > bv || (ov == bv && oi < bi)) { bv = ov; bi = oi; }
    }
    if (lane == 0) { rv[wid] = bv; ri[wid] = bi; }
    __syncthreads();
    if (wid == 0) {
        float v = (lane < nw) ? rv[lane] : -INFINITY;
        int ix = (lane < nw) ? ri[lane] : 0x7fffffff;
#pragma unroll
        for (int off = 1; off < 16; off <<= 1) {
            const float ov = __shfl_xor(v, off);
            const int oi = __shfl_xor(ix, off);
            if (ov > v || (ov == v && oi < ix)) { v = ov; ix = oi; }
        }
        if (lane == 0) { rv[0] = v; ri[0] = ix; }
    }
    __syncthreads();
    bv = rv[0];
    bi = ri[0];
}

__global__ __launch_bounds__(1024) void k_path_fly(const float* __restrict__ emb,
                                                   const float* __restrict__ A,
                                                   const float* __restrict__ Cc,
                                                   const float* __restrict__ w2g,
                                                   const float* __restrict__ b2p,
                                                   float* __restrict__ out) {
    const int g = blockIdx.x;
    const int tid = threadIdx.x;
    const int lane = tid & 63, wid = tid >> 6;
    __shared__ float acur[H_], w2s[H_];
    __shared__ unsigned char vis[N_];
    __shared__ float rv[16];
    __shared__ int ri[16];
    const float b2v = *b2p;
    if (tid < H_) w2s[tid] = w2g[tid];
    for (int j = tid; j < N_; j += 1024) vis[j] = 0;

    float bv = -INFINITY;
    int bi = 0x7fffffff;
    for (int j = tid; j < N_; j += 1024) {
        const float v = emb[((size_t)g * N_ + j) * H_];
        if (v > bv) { bv = v; bi = j; }
    }
    __syncthreads();
    blockArgmax(bv, bi, rv, ri, lane, wid, 16);
    int cur = bi;
    float* pathOut = out + (size_t)g * N_;
    float* scoreOut = out + (size_t)BN_ + (size_t)g * N_;
    if (tid == 0) {
        vis[cur] = 1;
        pathOut[0] = (float)cur;
        scoreOut[0] = 1.0f;
    }
    __syncthreads();

    int t = 1;
    for (; t < N_; ++t) {
        if (tid < H_) acur[tid] = A[((size_t)g * N_ + cur) * H_ + tid];
        __syncthreads();
        float mbv = -INFINITY;
        int mbi = 0x7fffffff;
#pragma unroll
        for (int q = 0; q < 2; ++q) {
            const int j = tid + q * 1024;
            const float* Cj = Cc + ((size_t)g * N_ + j) * H_;
            float p = 0.f;
            for (int h = 0; h < H_; h += 4) {
                const float4 c = *(const float4*)(Cj + h);
                p = fmaf(w2s[h + 0], elu1(acur[h + 0] + c.x), p);
                p = fmaf(w2s[h + 1], elu1(acur[h + 1] + c.y), p);
                p = fmaf(w2s[h + 2], elu1(acur[h + 2] + c.z), p);
                p = fmaf(w2s[h + 3], elu1(acur[h + 3] + c.w), p);
            }
            const float z = p + b2v;
            if (!vis[j] && (z > mbv || (z == mbv && j < mbi))) { mbv = z; mbi = j; }
        }
        __syncthreads();
        blockArgmax(mbv, mbi, rv, ri, lane, wid, 16);
        const float s = 1.f / (1.f + expf(-mbv));
        if (!((double)s > 0.3)) break;
        cur = mbi;
        if (tid == 0) {
            vis[cur] = 1;
            pathOut[t] = (float)cur;
            scoreOut[t] = s;
        }
        __syncthreads();
    }
    for (int tt = t + tid; tt < N_; tt += 1024) {
        pathOut[tt] = -1.f;
        scoreOut[tt] = 0.f;
    }
}

extern "C" void kernel_launch(void* const* d_in, const int* in_sizes, int n_in,
                              void* d_out, int out_size, void* d_ws, size_t ws_size,
                              hipStream_t stream) {
    (void)in_sizes; (void)n_in; (void)out_size;
    const float* emb = (const float*)d_in[0];
    // d_in[1] = batch (int64) — contiguous equal-sized graphs, unused
    const float* W1 = (const float*)d_in[2];
    const float* b1 = (const float*)d_in[3];
    const float* w2 = (const float*)d_in[4];
    const float* b2 = (const float*)d_in[5];
    float* out = (float*)d_out;

    float* A = (float*)d_ws;
    float* C = A + (size_t)BN_ * H_;
    unsigned* K = (unsigned*)(C + (size_t)BN_ * H_);
    const size_t need = ((size_t)BN_ * H_ * 2 + (size_t)B_ * N_ * N_) * sizeof(float);

    hipLaunchKernelGGL(k_ac, dim3(BN_), dim3(H_), 0, stream, emb, W1, b1, A, C);
    if (ws_size >= need) {
        hipLaunchKernelGGL(k_z, dim3(2048), dim3(256), 0, stream, A, C, w2, b2, K);
        hipLaunchKernelGGL(k_path5, dim3(B_), dim3(64), 0, stream, emb, K, out);
    } else {
        hipLaunchKernelGGL(k_path_fly, dim3(B_), dim3(1024), 0, stream,
                           emb, A, C, w2, b2, out);
    }
}